// Round 19
// baseline (5103.880 us; speedup 1.0000x reference)
//
#include <hip/hip_runtime.h>
#include <hip/hip_bf16.h>
#include <math.h>

#define Tn   2048
#define Cn   1536
#define Vn   32000
#define NHn  12
#define NKVn 4
#define Dn   128
#define HIDn 2048
#define En   8
#define Kn   2
#define Ln   2
#define NREPn 3
#define EPSn 1e-6f
#define CHT  8
#define TOTCH 288
#define QKVW 2560

using bf16 = __hip_bfloat16;
using bf16x8 = __attribute__((ext_vector_type(8))) short;
using f32x4v = __attribute__((ext_vector_type(4))) float;

__device__ __forceinline__ void split3(float v, short& h, short& m, short& lo) {
  bf16 b0 = __float2bfloat16(v);
  float r1 = v - __bfloat162float(b0);
  bf16 b1 = __float2bfloat16(r1);
  float r2 = r1 - __bfloat162float(b1);
  bf16 b2 = __float2bfloat16(r2);
  h = *reinterpret_cast<short*>(&b0);
  m = *reinterpret_cast<short*>(&b1);
  lo = *reinterpret_cast<short*>(&b2);
}
__device__ __forceinline__ float b2f(short s) {
  bf16 b = *reinterpret_cast<bf16*>(&s);
  return __bfloat162float(b);
}
__device__ __forceinline__ void gl_lds16(const void* g, void* l) {
  __builtin_amdgcn_global_load_lds((const __attribute__((address_space(1))) void*)g,
                                   (__attribute__((address_space(3))) void*)l, 16, 0, 0);
}

// ---------------- embed (validated) ----------------
__global__ void embed_k(const int* __restrict__ tok, const float* __restrict__ emb,
                        const float* __restrict__ pos, float* __restrict__ x) {
  int n = blockIdx.x;
  int t = threadIdx.x;
  int id = tok[n];
  const float* er = emb + (size_t)id * Cn;
  const float* pr = pos + (size_t)n * Cn;
  float* xr = x + (size_t)n * Cn;
  for (int c = t; c < Cn; c += 256) xr[c] = er[c] + pr[c];
}

// ---------------- RMSNorm -> (opt fp32) + 3-level split (validated) ----------------
__global__ void rms3_k(const float* __restrict__ x, const float* __restrict__ w,
                       float* __restrict__ outf, short* __restrict__ dh,
                       short* __restrict__ dm, short* __restrict__ dl) {
  int n = blockIdx.x, t = threadIdx.x;
  const float* xr = x + (size_t)n * Cn;
  float v[6];
  float ss = 0.f;
#pragma unroll
  for (int i = 0; i < 6; i++) { v[i] = xr[t + i * 256]; ss += v[i] * v[i]; }
  for (int off = 32; off > 0; off >>= 1) ss += __shfl_down(ss, off, 64);
  __shared__ float red[4];
  __shared__ float rtot;
  int wave = t >> 6, lane = t & 63;
  if (lane == 0) red[wave] = ss;
  __syncthreads();
  if (t == 0) rtot = rsqrtf((red[0] + red[1] + red[2] + red[3]) / (float)Cn + EPSn);
  __syncthreads();
  float r = rtot;
#pragma unroll
  for (int i = 0; i < 6; i++) {
    int c = t + i * 256;
    float val = v[i] * r * w[c];
    size_t idx = (size_t)n * Cn + c;
    if (outf) outf[idx] = val;
    short h, m, lo;
    split3(val, h, m, lo);
    dh[idx] = h; dm[idx] = m; dl[idx] = lo;
  }
}

// ---------------- RMSNorm -> (opt fp32) + bf16 (validated) ----------------
__global__ void rmsb_k(const float* __restrict__ x, const float* __restrict__ w,
                       float* __restrict__ outf, bf16* __restrict__ outb) {
  int n = blockIdx.x, t = threadIdx.x;
  const float* xr = x + (size_t)n * Cn;
  float v[6];
  float ss = 0.f;
#pragma unroll
  for (int i = 0; i < 6; i++) { v[i] = xr[t + i * 256]; ss += v[i] * v[i]; }
  for (int off = 32; off > 0; off >>= 1) ss += __shfl_down(ss, off, 64);
  __shared__ float red[4];
  __shared__ float rtot;
  int wave = t >> 6, lane = t & 63;
  if (lane == 0) red[wave] = ss;
  __syncthreads();
  if (t == 0) rtot = rsqrtf((red[0] + red[1] + red[2] + red[3]) / (float)Cn + EPSn);
  __syncthreads();
  float r = rtot;
#pragma unroll
  for (int i = 0; i < 6; i++) {
    int c = t + i * 256;
    float val = v[i] * r * w[c];
    size_t idx = (size_t)n * Cn + c;
    if (outf) outf[idx] = val;
    outb[idx] = __float2bfloat16(val);
  }
}

// ---------------- fp32 -> bf16 (validated) ----------------
__global__ void f2b_k(const float* __restrict__ s, bf16* __restrict__ d, size_t n4) {
  size_t i = (size_t)blockIdx.x * 256 + threadIdx.x;
  size_t stride = (size_t)gridDim.x * 256;
  for (; i < n4; i += stride) {
    float4 v = ((const float4*)s)[i];
    d[i * 4 + 0] = __float2bfloat16(v.x);
    d[i * 4 + 1] = __float2bfloat16(v.y);
    d[i * 4 + 2] = __float2bfloat16(v.z);
    d[i * 4 + 3] = __float2bfloat16(v.w);
  }
}

// ---------------- transpose + 3-way split (validated) ----------------
__global__ void transp3_k(const float* __restrict__ src, short* __restrict__ dh,
                          short* __restrict__ dm, short* __restrict__ dl, int K, int N) {
  __shared__ __align__(16) float ls[32][33];
  size_t boff = (size_t)blockIdx.z * K * N;
  int k0 = blockIdx.x * 32, n0 = blockIdx.y * 32;
  int t = threadIdx.x;
  int kr = t >> 3, n4 = (t & 7) * 4;
  float4 vv = *(const float4*)&src[boff + (size_t)(k0 + kr) * N + n0 + n4];
  ls[kr][n4 + 0] = vv.x; ls[kr][n4 + 1] = vv.y; ls[kr][n4 + 2] = vv.z; ls[kr][n4 + 3] = vv.w;
  __syncthreads();
  int nr = t >> 3, k4 = (t & 7) * 4;
  size_t dbase = boff + (size_t)(n0 + nr) * K + k0 + k4;
#pragma unroll
  for (int u = 0; u < 4; u++) {
    short h, m, lo;
    split3(ls[k4 + u][nr], h, m, lo);
    dh[dbase + u] = h; dm[dbase + u] = m; dl[dbase + u] = lo;
  }
}

// ---------------- single-level transpose+convert (validated) ----------------
__global__ void transp_k(const float* __restrict__ src, bf16* __restrict__ dst, int K, int N) {
  __shared__ __align__(16) float ls[32][33];
  size_t boff = (size_t)blockIdx.z * K * N;
  int k0 = blockIdx.x * 32, n0 = blockIdx.y * 32;
  int t = threadIdx.x;
  int kr = t >> 3, n4 = (t & 7) * 4;
  float4 vv = *(const float4*)&src[boff + (size_t)(k0 + kr) * N + n0 + n4];
  ls[kr][n4 + 0] = vv.x; ls[kr][n4 + 1] = vv.y; ls[kr][n4 + 2] = vv.z; ls[kr][n4 + 3] = vv.w;
  __syncthreads();
  int nr = t >> 3, k4 = (t & 7) * 4;
  bf16* drow = dst + boff + (size_t)(n0 + nr) * K + k0 + k4;
#pragma unroll
  for (int u = 0; u < 4; u++) drow[u] = __float2bfloat16(ls[k4 + u][nr]);
}

// ---------------- LDS-staged pure-bf16 MFMA GEMM (validated; logits tail) ----------------
__global__ void __launch_bounds__(256) gemm_btl(const bf16* __restrict__ A, const bf16* __restrict__ Bt,
                                                const float* res, float* Co, int M, int N, int K) {
  __shared__ __align__(16) bf16 As[128 * 32];
  __shared__ __align__(16) bf16 Bs[128 * 32];
  int t = threadIdx.x;
  int l = t & 63, w = t >> 6;
  int bm = blockIdx.x * 128, bn = blockIdx.y * 128;
  int wr = (w >> 1) * 64, wc = (w & 1) * 64;
  const f32x4v zero = {0.f, 0.f, 0.f, 0.f};
  f32x4v acc[4][4];
#pragma unroll
  for (int i = 0; i < 4; i++)
#pragma unroll
    for (int j = 0; j < 4; j++) acc[i][j] = zero;
  const bf16* ag0 = A + (size_t)(bm + (t >> 2)) * K + (t & 3) * 8;
  const bf16* ag1 = A + (size_t)(bm + 64 + (t >> 2)) * K + (t & 3) * 8;
  const bf16* bg0 = Bt + (size_t)(bn + (t >> 2)) * K + (t & 3) * 8;
  const bf16* bg1 = Bt + (size_t)(bn + 64 + (t >> 2)) * K + (t & 3) * 8;
  int rl = l & 15, ko = (l >> 4) * 8;
  for (int k0 = 0; k0 < K; k0 += 32) {
    gl_lds16(ag0 + k0, (char*)As + t * 16);
    gl_lds16(ag1 + k0, (char*)As + (256 + t) * 16);
    gl_lds16(bg0 + k0, (char*)Bs + t * 16);
    gl_lds16(bg1 + k0, (char*)Bs + (256 + t) * 16);
    __syncthreads();
    bf16x8 a[4], b[4];
#pragma unroll
    for (int i = 0; i < 4; i++) a[i] = *(const bf16x8*)(As + (wr + i * 16 + rl) * 32 + ko);
#pragma unroll
    for (int j = 0; j < 4; j++) b[j] = *(const bf16x8*)(Bs + (wc + j * 16 + rl) * 32 + ko);
#pragma unroll
    for (int i = 0; i < 4; i++)
#pragma unroll
      for (int j = 0; j < 4; j++)
        acc[i][j] = __builtin_amdgcn_mfma_f32_16x16x32_bf16(a[i], b[j], acc[i][j], 0, 0, 0);
    __syncthreads();
  }
#pragma unroll
  for (int i = 0; i < 4; i++) {
    int rbase = bm + wr + i * 16 + (l >> 4) * 4;
#pragma unroll
    for (int j = 0; j < 4; j++) {
      int col = bn + wc + j * 16 + (l & 15);
#pragma unroll
      for (int r = 0; r < 4; r++) {
        size_t idx = (size_t)(rbase + r) * N + col;
        float v = acc[i][j][r];
        if (res) v += res[idx];
        Co[idx] = v;
      }
    }
  }
}

// ---------------- LDS-staged split-fp32 GEMM (validated) ----------------
__global__ void __launch_bounds__(256) gemm6(const bf16* __restrict__ AH, const bf16* __restrict__ AM,
                                             const bf16* __restrict__ AL,
                                             const bf16* __restrict__ BH, const bf16* __restrict__ BM,
                                             const bf16* __restrict__ BL,
                                             const float* res, float* __restrict__ Co,
                                             int M, int N, int K) {
  __shared__ __align__(16) bf16 sAH[128 * 32], sAM[128 * 32], sAL[128 * 32];
  __shared__ __align__(16) bf16 sBH[128 * 32], sBM[128 * 32], sBL[128 * 32];
  int t = threadIdx.x;
  int l = t & 63, w = t >> 6;
  int bm = blockIdx.x * 128, bn = blockIdx.y * 128;
  int wr = (w >> 1) * 64, wc = (w & 1) * 64;
  const f32x4v zero = {0.f, 0.f, 0.f, 0.f};
  f32x4v acc[4][4];
#pragma unroll
  for (int i = 0; i < 4; i++)
#pragma unroll
    for (int j = 0; j < 4; j++) acc[i][j] = zero;
  size_t a0 = (size_t)(bm + (t >> 2)) * K + (t & 3) * 8;
  size_t a1 = (size_t)(bm + 64 + (t >> 2)) * K + (t & 3) * 8;
  size_t b0 = (size_t)(bn + (t >> 2)) * K + (t & 3) * 8;
  size_t b1 = (size_t)(bn + 64 + (t >> 2)) * K + (t & 3) * 8;
  int rl = l & 15, ko = (l >> 4) * 8;
  for (int k0 = 0; k0 < K; k0 += 32) {
    gl_lds16(AH + a0 + k0, (char*)sAH + t * 16);
    gl_lds16(AH + a1 + k0, (char*)sAH + (256 + t) * 16);
    gl_lds16(AM + a0 + k0, (char*)sAM + t * 16);
    gl_lds16(AM + a1 + k0, (char*)sAM + (256 + t) * 16);
    gl_lds16(AL + a0 + k0, (char*)sAL + t * 16);
    gl_lds16(AL + a1 + k0, (char*)sAL + (256 + t) * 16);
    gl_lds16(BH + b0 + k0, (char*)sBH + t * 16);
    gl_lds16(BH + b1 + k0, (char*)sBH + (256 + t) * 16);
    gl_lds16(BM + b0 + k0, (char*)sBM + t * 16);
    gl_lds16(BM + b1 + k0, (char*)sBM + (256 + t) * 16);
    gl_lds16(BL + b0 + k0, (char*)sBL + t * 16);
    gl_lds16(BL + b1 + k0, (char*)sBL + (256 + t) * 16);
    __syncthreads();
    bf16x8 aH[4], aM[4], aL[4];
#pragma unroll
    for (int i = 0; i < 4; i++) {
      int ro = (wr + i * 16 + rl) * 32 + ko;
      aH[i] = *(const bf16x8*)(sAH + ro);
      aM[i] = *(const bf16x8*)(sAM + ro);
      aL[i] = *(const bf16x8*)(sAL + ro);
    }
#pragma unroll
    for (int j = 0; j < 4; j++) {
      int ro = (wc + j * 16 + rl) * 32 + ko;
      bf16x8 bh = *(const bf16x8*)(sBH + ro);
      bf16x8 bm_ = *(const bf16x8*)(sBM + ro);
      bf16x8 bl = *(const bf16x8*)(sBL + ro);
#pragma unroll
      for (int i = 0; i < 4; i++) {
        acc[i][j] = __builtin_amdgcn_mfma_f32_16x16x32_bf16(aL[i], bh, acc[i][j], 0, 0, 0);
        acc[i][j] = __builtin_amdgcn_mfma_f32_16x16x32_bf16(aH[i], bl, acc[i][j], 0, 0, 0);
        acc[i][j] = __builtin_amdgcn_mfma_f32_16x16x32_bf16(aM[i], bm_, acc[i][j], 0, 0, 0);
        acc[i][j] = __builtin_amdgcn_mfma_f32_16x16x32_bf16(aM[i], bh, acc[i][j], 0, 0, 0);
        acc[i][j] = __builtin_amdgcn_mfma_f32_16x16x32_bf16(aH[i], bm_, acc[i][j], 0, 0, 0);
        acc[i][j] = __builtin_amdgcn_mfma_f32_16x16x32_bf16(aH[i], bh, acc[i][j], 0, 0, 0);
      }
    }
    __syncthreads();
  }
#pragma unroll
  for (int i = 0; i < 4; i++) {
    int rbase = bm + wr + i * 16 + (l >> 4) * 4;
#pragma unroll
    for (int j = 0; j < 4; j++) {
      int col = bn + wc + j * 16 + (l & 15);
#pragma unroll
      for (int r = 0; r < 4; r++) {
        size_t idx = (size_t)(rbase + r) * N + col;
        float v = acc[i][j][r];
        if (res) v += res[idx];
        Co[idx] = v;
      }
    }
  }
}

// ---------------- LDS-staged split-fp32 MoE expert GEMM (validated; layer 0) ----------------
__global__ void __launch_bounds__(256) mexp6(const bf16* __restrict__ AH, const bf16* __restrict__ AM,
                                             const bf16* __restrict__ AL,
                                             const bf16* __restrict__ BH, const bf16* __restrict__ BM,
                                             const bf16* __restrict__ BL,
                                             const int* __restrict__ perm, const int* __restrict__ cnt,
                                             int ebase,
                                             short* __restrict__ HH, short* __restrict__ HM,
                                             short* __restrict__ HL,
                                             float* __restrict__ Co, int K, int N, int mode) {
  int e = ebase + blockIdx.z;
  int nrows = cnt[e];
  int bm = blockIdx.x * 128;
  if (bm >= nrows) return;
  int bn = blockIdx.y * 128;
  size_t eoff = (size_t)blockIdx.z * K * N;
  __shared__ __align__(16) bf16 sAH[128 * 32], sAM[128 * 32], sAL[128 * 32];
  __shared__ __align__(16) bf16 sBH[128 * 32], sBM[128 * 32], sBL[128 * 32];
  __shared__ int prow[128];
  int t = threadIdx.x, l = t & 63, w = t >> 6;
  if (t < 128) {
    int i = bm + t;
    prow[t] = (i < nrows) ? perm[e * Tn + i] : -1;
  }
  __syncthreads();
  int wr = (w >> 1) * 64, wc = (w & 1) * 64;
  const f32x4v zero = {0.f, 0.f, 0.f, 0.f};
  f32x4v acc[4][4];
#pragma unroll
  for (int i = 0; i < 4; i++)
#pragma unroll
    for (int j = 0; j < 4; j++) acc[i][j] = zero;
  int p0 = prow[t >> 2], p1 = prow[64 + (t >> 2)];
  int g0r = (p0 >= 0) ? (mode == 2 ? p0 : (p0 >> 1)) : 0;
  int g1r = (p1 >= 0) ? (mode == 2 ? p1 : (p1 >> 1)) : 0;
  size_t a0 = (size_t)g0r * K + (t & 3) * 8;
  size_t a1 = (size_t)g1r * K + (t & 3) * 8;
  size_t b0 = eoff + (size_t)(bn + (t >> 2)) * K + (t & 3) * 8;
  size_t b1 = eoff + (size_t)(bn + 64 + (t >> 2)) * K + (t & 3) * 8;
  int rl = l & 15, ko = (l >> 4) * 8;
  for (int k0 = 0; k0 < K; k0 += 32) {
    gl_lds16(AH + a0 + k0, (char*)sAH + t * 16);
    gl_lds16(AH + a1 + k0, (char*)sAH + (256 + t) * 16);
    gl_lds16(AM + a0 + k0, (char*)sAM + t * 16);
    gl_lds16(AM + a1 + k0, (char*)sAM + (256 + t) * 16);
    gl_lds16(AL + a0 + k0, (char*)sAL + t * 16);
    gl_lds16(AL + a1 + k0, (char*)sAL + (256 + t) * 16);
    gl_lds16(BH + b0 + k0, (char*)sBH + t * 16);
    gl_lds16(BH + b1 + k0, (char*)sBH + (256 + t) * 16);
    gl_lds16(BM + b0 + k0, (char*)sBM + t * 16);
    gl_lds16(BM + b1 + k0, (char*)sBM + (256 + t) * 16);
    gl_lds16(BL + b0 + k0, (char*)sBL + t * 16);
    gl_lds16(BL + b1 + k0, (char*)sBL + (256 + t) * 16);
    __syncthreads();
    bf16x8 aH[4], aM[4], aL[4];
#pragma unroll
    for (int i = 0; i < 4; i++) {
      int ro = (wr + i * 16 + rl) * 32 + ko;
      aH[i] = *(const bf16x8*)(sAH + ro);
      aM[i] = *(const bf16x8*)(sAM + ro);
      aL[i] = *(const bf16x8*)(sAL + ro);
    }
#pragma unroll
    for (int j = 0; j < 4; j++) {
      int ro = (wc + j * 16 + rl) * 32 + ko;
      bf16x8 bh = *(const bf16x8*)(sBH + ro);
      bf16x8 bm_ = *(const bf16x8*)(sBM + ro);
      bf16x8 bl = *(const bf16x8*)(sBL + ro);
#pragma unroll
      for (int i = 0; i < 4; i++) {
        acc[i][j] = __builtin_amdgcn_mfma_f32_16x16x32_bf16(aL[i], bh, acc[i][j], 0, 0, 0);
        acc[i][j] = __builtin_amdgcn_mfma_f32_16x16x32_bf16(aH[i], bl, acc[i][j], 0, 0, 0);
        acc[i][j] = __builtin_amdgcn_mfma_f32_16x16x32_bf16(aM[i], bm_, acc[i][j], 0, 0, 0);
        acc[i][j] = __builtin_amdgcn_mfma_f32_16x16x32_bf16(aM[i], bh, acc[i][j], 0, 0, 0);
        acc[i][j] = __builtin_amdgcn_mfma_f32_16x16x32_bf16(aH[i], bm_, acc[i][j], 0, 0, 0);
        acc[i][j] = __builtin_amdgcn_mfma_f32_16x16x32_bf16(aH[i], bh, acc[i][j], 0, 0, 0);
      }
    }
    __syncthreads();
  }
#pragma unroll
  for (int i = 0; i < 4; i++) {
#pragma unroll
    for (int r = 0; r < 4; r++) {
      int lrow = wr + i * 16 + (l >> 4) * 4 + r;
      int p = prow[lrow];
      if (p < 0) continue;
#pragma unroll
      for (int j = 0; j < 4; j++) {
        int col = bn + wc + j * 16 + (l & 15);
        size_t idx = (size_t)p * N + col;
        float v = acc[i][j][r];
        if (mode == 0) {
          short h, m, lo;
          split3(v, h, m, lo);
          HH[idx] = h; HM[idx] = m; HL[idx] = lo;
        } else if (mode == 1) {
          float v1 = b2f(HH[idx]) + b2f(HM[idx]) + b2f(HL[idx]);
          float hh = (v1 / (1.f + expf(-v1))) * v;
          short h, m, lo;
          split3(hh, h, m, lo);
          HH[idx] = h; HM[idx] = m; HL[idx] = lo;
        } else {
          Co[idx] = v;
        }
      }
    }
  }
}

// ---------------- DUAL-B bf16 MoE up-proj (validated; layer 1) ----------------
__global__ void __launch_bounds__(256) mexpBd(const bf16* __restrict__ A, const bf16* __restrict__ B1,
                                              const bf16* __restrict__ B3,
                                              const int* __restrict__ perm, const int* __restrict__ cnt,
                                              int ebase, bf16* __restrict__ HB, int K, int N) {
  int e = ebase + blockIdx.z;
  int nrows = cnt[e];
  int bm = blockIdx.x * 128;
  if (bm >= nrows) return;
  int bn = blockIdx.y * 128;
  size_t eoff = (size_t)blockIdx.z * K * N;
  __shared__ __align__(16) bf16 sA[128 * 32];
  __shared__ __align__(16) bf16 s1[128 * 32];
  __shared__ __align__(16) bf16 s3[128 * 32];
  __shared__ int prow[128];
  int t = threadIdx.x, l = t & 63, w = t >> 6;
  if (t < 128) {
    int i = bm + t;
    prow[t] = (i < nrows) ? perm[e * Tn + i] : -1;
  }
  __syncthreads();
  int wr = (w >> 1) * 64, wc = (w & 1) * 64;
  const f32x4v zero = {0.f, 0.f, 0.f, 0.f};
  f32x4v acc1[4][4], acc3[4][4];
#pragma unroll
  for (int i = 0; i < 4; i++)
#pragma unroll
    for (int j = 0; j < 4; j++) { acc1[i][j] = zero; acc3[i][j] = zero; }
  int p0 = prow[t >> 2], p1 = prow[64 + (t >> 2)];
  int g0r = (p0 >= 0) ? (p0 >> 1) : 0;
  int g1r = (p1 >= 0) ? (p1 >> 1) : 0;
  size_t a0 = (size_t)g0r * K + (t & 3) * 8;
  size_t a1 = (size_t)g1r * K + (t & 3) * 8;
  size_t b0 = eoff + (size_t)(bn + (t >> 2)) * K + (t & 3) * 8;
  size_t b1 = eoff + (size_t)(bn + 64 + (t >> 2)) * K + (t & 3) * 8;
  int rl = l & 15, ko = (l >> 4) * 8;
  for (int k0 = 0; k0 < K; k0 += 32) {
    gl_lds16(A + a0 + k0, (char*)sA + t * 16);
    gl_lds16(A + a1 + k0, (char*)sA + (256 + t) * 16);
    gl_lds16(B1 + b0 + k0, (char*)s1 + t * 16);
    gl_lds16(B1 + b1 + k0, (char*)s1 + (256 + t) * 16);
    gl_lds16(B3 + b0 + k0, (char*)s3 + t * 16);
    gl_lds16(B3 + b1 + k0, (char*)s3 + (256 + t) * 16);
    __syncthreads();
    bf16x8 a[4];
#pragma unroll
    for (int i = 0; i < 4; i++) a[i] = *(const bf16x8*)(sA + (wr + i * 16 + rl) * 32 + ko);
#pragma unroll
    for (int j = 0; j < 4; j++) {
      int ro = (wc + j * 16 + rl) * 32 + ko;
      bf16x8 b1v = *(const bf16x8*)(s1 + ro);
      bf16x8 b3v = *(const bf16x8*)(s3 + ro);
#pragma unroll
      for (int i = 0; i < 4; i++) {
        acc1[i][j] = __builtin_amdgcn_mfma_f32_16x16x32_bf16(a[i], b1v, acc1[i][j], 0, 0, 0);
        acc3[i][j] = __builtin_amdgcn_mfma_f32_16x16x32_bf16(a[i], b3v, acc3[i][j], 0, 0, 0);
      }
    }
    __syncthreads();
  }
#pragma unroll
  for (int i = 0; i < 4; i++) {
#pragma unroll
    for (int r = 0; r < 4; r++) {
      int lrow = wr + i * 16 + (l >> 4) * 4 + r;
      int p = prow[lrow];
      if (p < 0) continue;
#pragma unroll
      for (int j = 0; j < 4; j++) {
        int col = bn + wc + j * 16 + (l & 15);
        float h1 = acc1[i][j][r], h3 = acc3[i][j][r];
        HB[(size_t)p * N + col] = __float2bfloat16((h1 / (1.f + expf(-h1))) * h3);
      }
    }
  }
}

// ---------------- bf16 MoE expert GEMM (validated; layer-1 down-proj) ----------------
__global__ void __launch_bounds__(256) mexpB(const bf16* __restrict__ A, const bf16* __restrict__ B,
                                             const int* __restrict__ perm, const int* __restrict__ cnt,
                                             int ebase, float* __restrict__ Co, int K, int N) {
  int e = ebase + blockIdx.z;
  int nrows = cnt[e];
  int bm = blockIdx.x * 128;
  if (bm >= nrows) return;
  int bn = blockIdx.y * 128;
  size_t eoff = (size_t)blockIdx.z * K * N;
  __shared__ __align__(16) bf16 sA[128 * 32];
  __shared__ __align__(16) bf16 sB[128 * 32];
  __shared__ int prow[128];
  int t = threadIdx.x, l = t & 63, w = t >> 6;
  if (t < 128) {
    int i = bm + t;
    prow[t] = (i < nrows) ? perm[e * Tn + i] : -1;
  }
  __syncthreads();
  int wr = (w >> 1) * 64, wc = (w & 1) * 64;
  const f32x4v zero = {0.f, 0.f, 0.f, 0.f};
  f32x4v acc[4][4];
#pragma unroll
  for (int i = 0; i < 4; i++)
#pragma unroll
    for (int j = 0; j < 4; j++) acc[i][j] = zero;
  int p0 = prow[t >> 2], p1 = prow[64 + (t >> 2)];
  int g0r = (p0 >= 0) ? p0 : 0;
  int g1r = (p1 >= 0) ? p1 : 0;
  size_t a0 = (size_t)g0r * K + (t & 3) * 8;
  size_t a1 = (size_t)g1r * K + (t & 3) * 8;
  size_t b0 = eoff + (size_t)(bn + (t >> 2)) * K + (t & 3) * 8;
  size_t b1 = eoff + (size_t)(bn + 64 + (t >> 2)) * K + (t & 3) * 8;
  int rl = l & 15, ko = (l >> 4) * 8;
  for (int k0 = 0; k0 < K; k0 += 32) {
    gl_lds16(A + a0 + k0, (char*)sA + t * 16);
    gl_lds16(A + a1 + k0, (char*)sA + (256 + t) * 16);
    gl_lds16(B + b0 + k0, (char*)sB + t * 16);
    gl_lds16(B + b1 + k0, (char*)sB + (256 + t) * 16);
    __syncthreads();
    bf16x8 a[4], b[4];
#pragma unroll
    for (int i = 0; i < 4; i++) a[i] = *(const bf16x8*)(sA + (wr + i * 16 + rl) * 32 + ko);
#pragma unroll
    for (int j = 0; j < 4; j++) b[j] = *(const bf16x8*)(sB + (wc + j * 16 + rl) * 32 + ko);
#pragma unroll
    for (int i = 0; i < 4; i++)
#pragma unroll
      for (int j = 0; j < 4; j++)
        acc[i][j] = __builtin_amdgcn_mfma_f32_16x16x32_bf16(a[i], b[j], acc[i][j], 0, 0, 0);
    __syncthreads();
  }
#pragma unroll
  for (int i = 0; i < 4; i++) {
#pragma unroll
    for (int r = 0; r < 4; r++) {
      int lrow = wr + i * 16 + (l >> 4) * 4 + r;
      int p = prow[lrow];
      if (p < 0) continue;
#pragma unroll
      for (int j = 0; j < 4; j++) {
        int col = bn + wc + j * 16 + (l & 15);
        Co[(size_t)p * N + col] = acc[i][j][r];
      }
    }
  }
}

// ---------------- split-K flash attention: VARIABLE-chunk partial pass (CHT=8, compact partials) ----------------
__global__ void __launch_bounds__(256) attn_part_k(const float* __restrict__ qkv,
                                                   float* __restrict__ po,
                                                   float* __restrict__ pm,
                                                   float* __restrict__ pl) {
  int c = blockIdx.x;         // flat chunk id in [0, TOTCH)
  int head = blockIdx.y;
  // decode (qt, ch): nch(qt) = qt/8 + 1; acc = prefix P(qt)
  int qt = 0, accp = 0;
  while (accp + (qt >> 3) + 1 <= c) { accp += (qt >> 3) + 1; qt++; }
  int ch = c - accp;
  int ntiles = qt + 1;
  int tA = ch * CHT;
  int tB = tA + CHT < ntiles ? tA + CHT : ntiles;
  int t = threadIdx.x;
  int r = t >> 3, g = t & 7, d0 = g * 16;
  int q0 = qt * 32;
  int row = q0 + r;
  size_t pidx = ((size_t)head * TOTCH + c) * 32 + r;
  int kvh = head / NREPn;
  __shared__ __align__(16) float ks[32][Dn + 4];
  __shared__ __align__(16) float vs[32][Dn + 4];
  const float scale = 0.08838834764831845f;
  float qr[16];
  {
    const float* qrow = qkv + (size_t)row * QKVW + head * Dn + d0;
#pragma unroll
    for (int j = 0; j < 16; j += 4) {
      float4 u = *(const float4*)(qrow + j);
      qr[j] = u.x * scale; qr[j + 1] = u.y * scale;
      qr[j + 2] = u.z * scale; qr[j + 3] = u.w * scale;
    }
  }
  float o[16];
#pragma unroll
  for (int j = 0; j < 16; j++) o[j] = 0.f;
  float rowm = -1e30f, rowl = 0.f;

  for (int kt = tA; kt < tB; kt++) {
    int kv0 = kt * 32;
    for (int e = t; e < 32 * 32; e += 256) {
      int rr = e >> 5, c4 = (e & 31) * 4;
      size_t base = (size_t)(kv0 + rr) * QKVW + kvh * Dn + c4;
      *(float4*)&ks[rr][c4] = *(const float4*)(qkv + base + 1536);
      *(float4*)&vs[rr][c4] = *(const float4*)(qkv + base + 2048);
    }
    __syncthreads();
    float s[32];
#pragma unroll
    for (int kk = 0; kk < 32; kk++) {
      const float* krow = &ks[kk][d0];
      float p = 0.f;
#pragma unroll
      for (int j = 0; j < 16; j += 4) {
        float4 u = *(const float4*)(krow + j);
        p += qr[j] * u.x + qr[j + 1] * u.y + qr[j + 2] * u.z + qr[j + 3] * u.w;
      }
      p += __shfl_xor(p, 1);
      p += __shfl_xor(p, 2);
      p += __shfl_xor(p, 4);
      s[kk] = p;
    }
    if (kt == qt) {
#pragma unroll
      for (int kk = 0; kk < 32; kk++)
        if (kv0 + kk > row) s[kk] = -1e30f;
    }
    float mx = s[0];
#pragma unroll
    for (int kk = 1; kk < 32; kk++) mx = fmaxf(mx, s[kk]);
    float m_new = fmaxf(rowm, mx);
    float corr = expf(rowm - m_new);
    float sum = 0.f;
#pragma unroll
    for (int kk = 0; kk < 32; kk++) { s[kk] = expf(s[kk] - m_new); sum += s[kk]; }
    rowl = rowl * corr + sum;
    rowm = m_new;
#pragma unroll
    for (int j = 0; j < 16; j++) o[j] *= corr;
#pragma unroll
    for (int kk = 0; kk < 32; kk++) {
      float p = s[kk];
      const float* vrow = &vs[kk][d0];
#pragma unroll
      for (int j = 0; j < 16; j += 4) {
        float4 u = *(const float4*)(vrow + j);
        o[j] += p * u.x; o[j + 1] += p * u.y; o[j + 2] += p * u.z; o[j + 3] += p * u.w;
      }
    }
    __syncthreads();
  }
  if (g == 0) { pm[pidx] = rowm; pl[pidx] = rowl; }
  float* porow = po + pidx * Dn + d0;
#pragma unroll
  for (int j = 0; j < 16; j += 4) {
    float4 u;
    u.x = o[j]; u.y = o[j + 1]; u.z = o[j + 2]; u.w = o[j + 3];
    *(float4*)(porow + j) = u;
  }
}

// ---------------- split-K merge (variable chunk count) -> split-3 levels ----------------
__global__ void __launch_bounds__(256) attn_merge3_k(const float* __restrict__ po,
                                                     const float* __restrict__ pm,
                                                     const float* __restrict__ pl,
                                                     short* __restrict__ dh,
                                                     short* __restrict__ dm,
                                                     short* __restrict__ dl) {
  int qt = blockIdx.x;
  int head = blockIdx.y;
  int q0 = qt * 32;
  int t = threadIdx.x;
  int r = t >> 3, g = t & 7, d0 = g * 16;
  int row = q0 + r;
  int f = qt >> 3, rr = qt & 7;
  int P = qt + 4 * f * (f - 1) + rr * f;      // prefix of chunk counts
  int nch = f + 1;                             // ceil((qt+1)/8)
  size_t base = ((size_t)head * TOTCH + P) * 32 + r;
  float M = -1e30f;
  for (int c = 0; c < nch; c++) M = fmaxf(M, pm[base + (size_t)c * 32]);
  float L = 0.f;
  float acc[16];
#pragma unroll
  for (int j = 0; j < 16; j++) acc[j] = 0.f;
  for (int c = 0; c < nch; c++) {
    size_t idx = base + (size_t)c * 32;
    float wgt = expf(pm[idx] - M);
    L += pl[idx] * wgt;
    const float* p = po + idx * Dn + d0;
#pragma unroll
    for (int j = 0; j < 16; j += 4) {
      float4 u = *(const float4*)(p + j);
      acc[j] += wgt * u.x; acc[j + 1] += wgt * u.y;
      acc[j + 2] += wgt * u.z; acc[j + 3] += wgt * u.w;
    }
  }
  float inv = 1.f / L;
  size_t yidx = (size_t)row * Cn + head * Dn + d0;
#pragma unroll
  for (int j = 0; j < 16; j++) {
    short h, m, lo;
    split3(acc[j] * inv, h, m, lo);
    dh[yidx + j] = h; dm[yidx + j] = m; dl[yidx + j] = lo;
  }
}

// ---------------- gate logits (validated) ----------------
__global__ void gate_k(const float* __restrict__ xf, const float* __restrict__ g,
                       float* __restrict__ gl) {
  int n = blockIdx.x, t = threadIdx.x;
  int e = t & 7, cs = t >> 3;
  const float* xr = xf + (size_t)n * Cn;
  float s = 0.f;
  for (int j = 0; j < Cn / 32; j++) {
    int c = cs + 32 * j;
    s += xr[c] * g[c * En + e];
  }
  __shared__ float red[256];
  red[t] = s;
  __syncthreads();
  if (t < 8) {
    float tot = 0.f;
    for (int j = 0; j < 32; j++) tot += red[t + 8 * j];
    gl[n * En + t] = tot;
  }
}

// ---------------- routing (validated, Tn stride) ----------------
__global__ void route_k(const float* __restrict__ gl, float* __restrict__ topw,
                        int* __restrict__ cnt, int* __restrict__ perm) {
  int n = blockIdx.x * blockDim.x + threadIdx.x;
  if (n >= Tn) return;
  float p[En];
  float mx = -1e30f;
#pragma unroll
  for (int e = 0; e < En; e++) { p[e] = gl[n * En + e]; mx = fmaxf(mx, p[e]); }
  float s = 0.f;
#pragma unroll
  for (int e = 0; e < En; e++) { p[e] = expf(p[e] - mx); s += p[e]; }
  float invs = 1.f / s;
#pragma unroll
  for (int e = 0; e < En; e++) p[e] *= invs;
  int i0 = 0;
#pragma unroll
  for (int e = 1; e < En; e++) if (p[e] > p[i0]) i0 = e;
  int i1 = (i0 == 0) ? 1 : 0;
#pragma unroll
  for (int e = 0; e < En; e++) if (e != i0 && p[e] > p[i1]) i1 = e;
  float w0 = p[i0], w1 = p[i1], sw = w0 + w1;
  topw[2 * n]     = w0 / sw;
  topw[2 * n + 1] = w1 / sw;
  int pos0 = atomicAdd(&cnt[i0], 1);
  perm[i0 * Tn + pos0] = 2 * n;
  int pos1 = atomicAdd(&cnt[i1], 1);
  perm[i1 * Tn + pos1] = 2 * n + 1;
}

// ---------------- combine (validated) ----------------
__global__ void combine_k(const float* __restrict__ pairout, const float* __restrict__ topw,
                          float* __restrict__ x) {
  int n = blockIdx.x, t = threadIdx.x;
  float w0 = topw[2 * n], w1 = topw[2 * n + 1];
  const float* p0 = pairout + (size_t)(2 * n) * Cn;
  const float* p1 = pairout + (size_t)(2 * n + 1) * Cn;
  float* xr = x + (size_t)n * Cn;
  for (int c = t; c < Cn; c += 256) xr[c] += w0 * p0[c] + w1 * p1[c];
}

// =================================================================================
extern "C" void kernel_launch(void* const* d_in, const int* in_sizes, int n_in,
                              void* d_out, int out_size, void* d_ws, size_t ws_size,
                              hipStream_t stream) {
  const int*   tokens = (const int*)d_in[0];
  const float* emb    = (const float*)d_in[1];
  const float* pos    = (const float*)d_in[2];
  const float* wq     = (const float*)d_in[3];
  const float* wk     = (const float*)d_in[4];
  const float* wv     = (const float*)d_in[5];
  const float* wo     = (const float*)d_in[6];
  const float* attn_nw= (const float*)d_in[7];
  const float* ffn_nw = (const float*)d_in[8];
  const float* gate   = (const float*)d_in[9];
  const float* ew1    = (const float*)d_in[10];
  const float* ew2    = (const float*)d_in[11];
  const float* ew3    = (const float*)d_in[12];
  const float* final_nw = (const float*)d_in[13];
  float* out = (float*)d_out;

  char* wsb = (char*)d_ws;
  const size_t NC = (size_t)Tn * Cn;
  size_t off = 0;
  auto alloc = [&](size_t bytes) -> size_t {
    off = (off + 255) & ~(size_t)255;
    size_t p = off;
    off += bytes;
    return p;
  };
  size_t o_x    = alloc(NC * 4);
  size_t o_h    = alloc(NC * 4);
  size_t o_gl   = alloc((size_t)Tn * En * 4);
  size_t o_topw = alloc((size_t)Tn * Kn * 4);
  size_t o_cnt  = alloc(64);
  size_t o_perm = alloc((size_t)En * Tn * 4);
  size_t wlvl   = (size_t)4 * Cn * HIDn * 2;
  size_t o_w    = alloc(3 * wlvl);
  size_t hs_lvl = NC * 2;
  size_t o_hs   = alloc(3 * hs_lvl);
  size_t o_qkv  = alloc((size_t)Tn * QKVW * 4);
  size_t o_yb   = alloc(NC * 4);
  size_t hb_lvl = (size_t)Tn * Kn * HIDn * 2;
  size_t o_hbs  = o_qkv;
  size_t end_hbs = o_hbs + 3 * hb_lvl;
  if (off < end_hbs) off = end_hbs;
  size_t o_pair = alloc(NC * 4);
  // compact variable-chunk partials: 12 heads x 288 chunk-slots x 32 rows x 128 = 56.6 MB
  size_t o_po   = alloc((size_t)NHn * TOTCH * 32 * Dn * 4);
  size_t o_pm   = alloc((size_t)NHn * TOTCH * 32 * 4);
  size_t o_pl   = alloc((size_t)NHn * TOTCH * 32 * 4);
  // total ~240 MB <= 264.4 MB proven

  float* x       = (float*)(wsb + o_x);
  float* h       = (float*)(wsb + o_h);
  float* gl      = (float*)(wsb + o_gl);
  float* topw    = (float*)(wsb + o_topw);
  int*   cnt     = (int*)(wsb + o_cnt);
  int*   perm    = (int*)(wsb + o_perm);
  float* qkvb    = (float*)(wsb + o_qkv);
  float* pairout = (float*)(wsb + o_pair);
  bf16*  hb      = (bf16*)(wsb + o_pair);
  bf16*  embB    = (bf16*)(wsb + o_w);
  float* po      = (float*)(wsb + o_po);
  float* pm      = (float*)(wsb + o_pm);
  float* pl      = (float*)(wsb + o_pl);

  short* hs[3]; short* hbs[3]; short* ewT[3];
  for (int s = 0; s < 3; s++) {
    hs[s]  = (short*)(wsb + o_hs + (size_t)s * hs_lvl);
    hbs[s] = (short*)(wsb + o_hbs + (size_t)s * hb_lvl);
    ewT[s] = (short*)(wsb + o_w + (size_t)s * wlvl);
  }
  size_t qkvw_lvl = (size_t)QKVW * Cn * 2;
  size_t wo_lvl   = (size_t)Cn * Cn * 2;
  short* qkvT[3]; short* woT[3];
  for (int s = 0; s < 3; s++) {
    qkvT[s] = (short*)(wsb + o_w + (size_t)s * qkvw_lvl);
    woT[s]  = (short*)(wsb + o_w + 3 * qkvw_lvl + (size_t)s * wo_lvl);
  }
  bf16* ew1B = (bf16*)(wsb + o_w);
  bf16* ew3B = (bf16*)(wsb + o_w + wlvl);
  bf16* ew2B = (bf16*)(wsb + o_w);

  embed_k<<<Tn, 256, 0, stream>>>(tokens, emb, pos, x);
  for (int l = 0; l < Ln; l++) {
    const float* wq_l = wq + (size_t)l * Cn * (NHn * Dn);
    const float* wk_l = wk + (size_t)l * Cn * (NKVn * Dn);
    const float* wv_l = wv + (size_t)l * Cn * (NKVn * Dn);
    const float* wo_l = wo + (size_t)l * Cn * Cn;
    const float* g_l  = gate + (size_t)l * Cn * En;
    const float* e1_l = ew1 + (size_t)l * En * Cn * HIDn;
    const float* e2_l = ew2 + (size_t)l * En * HIDn * Cn;
    const float* e3_l = ew3 + (size_t)l * En * Cn * HIDn;

    // --- attention: fused QKV split-GEMM + variable-chunk split-K fp32 core ---
    transp3_k<<<dim3(Cn / 32, (NHn * Dn) / 32, 1), 256, 0, stream>>>(wq_l, qkvT[0], qkvT[1], qkvT[2], Cn, NHn * Dn);
    transp3_k<<<dim3(Cn / 32, (NKVn * Dn) / 32, 1), 256, 0, stream>>>(
        wk_l, qkvT[0] + (size_t)1536 * Cn, qkvT[1] + (size_t)1536 * Cn, qkvT[2] + (size_t)1536 * Cn, Cn, NKVn * Dn);
    transp3_k<<<dim3(Cn / 32, (NKVn * Dn) / 32, 1), 256, 0, stream>>>(
        wv_l, qkvT[0] + (size_t)2048 * Cn, qkvT[1] + (size_t)2048 * Cn, qkvT[2] + (size_t)2048 * Cn, Cn, NKVn * Dn);
    transp3_k<<<dim3(Cn / 32, Cn / 32, 1), 256, 0, stream>>>(wo_l, woT[0], woT[1], woT[2], Cn, Cn);
    rms3_k<<<Tn, 256, 0, stream>>>(x, attn_nw + (size_t)l * Cn, nullptr, hs[0], hs[1], hs[2]);
    gemm6<<<dim3(Tn / 128, QKVW / 128), 256, 0, stream>>>(
        (bf16*)hs[0], (bf16*)hs[1], (bf16*)hs[2], (bf16*)qkvT[0], (bf16*)qkvT[1], (bf16*)qkvT[2],
        nullptr, qkvb, Tn, QKVW, Cn);
    attn_part_k<<<dim3(TOTCH, NHn), 256, 0, stream>>>(qkvb, po, pm, pl);
    attn_merge3_k<<<dim3(Tn / 32, NHn), 256, 0, stream>>>(po, pm, pl, hs[0], hs[1], hs[2]);
    gemm6<<<dim3(Tn / 128, Cn / 128), 256, 0, stream>>>(
        (bf16*)hs[0], (bf16*)hs[1], (bf16*)hs[2], (bf16*)woT[0], (bf16*)woT[1], (bf16*)woT[2],
        x, x, Tn, Cn, Cn);

    if (l < Ln - 1) {
      // --- layer-0 MoE: fp32 routing + three-pass split-fp32 experts ---
      rms3_k<<<Tn, 256, 0, stream>>>(x, ffn_nw + (size_t)l * Cn, h, hs[0], hs[1], hs[2]);
      gate_k<<<Tn, 256, 0, stream>>>(h, g_l, gl);
      hipMemsetAsync(cnt, 0, 64, stream);
      route_k<<<Tn / 256, 256, 0, stream>>>(gl, topw, cnt, perm);
      for (int half = 0; half < 2; half++) {
        size_t hoff = (size_t)half * 4 * Cn * HIDn;
        int eb = half * 4;
        transp3_k<<<dim3(Cn / 32, HIDn / 32, 4), 256, 0, stream>>>(e1_l + hoff, ewT[0], ewT[1], ewT[2], Cn, HIDn);
        mexp6<<<dim3(Tn / 128, HIDn / 128, 4), 256, 0, stream>>>(
            (bf16*)hs[0], (bf16*)hs[1], (bf16*)hs[2], (bf16*)ewT[0], (bf16*)ewT[1], (bf16*)ewT[2],
            perm, cnt, eb, hbs[0], hbs[1], hbs[2], nullptr, Cn, HIDn, 0);
        transp3_k<<<dim3(Cn / 32, HIDn / 32, 4), 256, 0, stream>>>(e3_l + hoff, ewT[0], ewT[1], ewT[2], Cn, HIDn);
        mexp6<<<dim3(Tn / 128, HIDn / 128, 4), 256, 0, stream>>>(
            (bf16*)hs[0], (bf16*)hs[1], (bf16*)hs[2], (bf16*)ewT[0], (bf16*)ewT[1], (bf16*)ewT[2],
            perm, cnt, eb, hbs[0], hbs[1], hbs[2], nullptr, Cn, HIDn, 1);
        transp3_k<<<dim3(HIDn / 32, Cn / 32, 4), 256, 0, stream>>>(e2_l + (size_t)half * 4 * HIDn * Cn, ewT[0], ewT[1], ewT[2], HIDn, Cn);
        mexp6<<<dim3(Tn / 128, Cn / 128, 4), 256, 0, stream>>>(
            (bf16*)hbs[0], (bf16*)hbs[1], (bf16*)hbs[2], (bf16*)ewT[0], (bf16*)ewT[1], (bf16*)ewT[2],
            perm, cnt, eb, hbs[0], hbs[1], hbs[2], pairout, HIDn, Cn, 2);
      }
    } else {
      // --- layer-1 MoE: fp32 routing + dual-B bf16 experts ---
      bf16* hbf = (bf16*)hs[0];
      bf16* hbB = (bf16*)hbs[0];
      rmsb_k<<<Tn, 256, 0, stream>>>(x, ffn_nw + (size_t)l * Cn, h, hbf);
      gate_k<<<Tn, 256, 0, stream>>>(h, g_l, gl);
      hipMemsetAsync(cnt, 0, 64, stream);
      route_k<<<Tn / 256, 256, 0, stream>>>(gl, topw, cnt, perm);
      for (int half = 0; half < 2; half++) {
        size_t hoff = (size_t)half * 4 * Cn * HIDn;
        int eb = half * 4;
        transp_k<<<dim3(Cn / 32, HIDn / 32, 4), 256, 0, stream>>>(e1_l + hoff, ew1B, Cn, HIDn);
        transp_k<<<dim3(Cn / 32, HIDn / 32, 4), 256, 0, stream>>>(e3_l + hoff, ew3B, Cn, HIDn);
        mexpBd<<<dim3(Tn / 128, HIDn / 128, 4), 256, 0, stream>>>(
            hbf, ew1B, ew3B, perm, cnt, eb, hbB, Cn, HIDn);
        transp_k<<<dim3(HIDn / 32, Cn / 32, 4), 256, 0, stream>>>(e2_l + (size_t)half * 4 * HIDn * Cn, ew2B, HIDn, Cn);
        mexpB<<<dim3(Tn / 128, Cn / 128, 4), 256, 0, stream>>>(
            hbB, ew2B, perm, cnt, eb, pairout, HIDn, Cn);
      }
    }
    combine_k<<<Tn, 256, 0, stream>>>(pairout, topw, x);
  }
  // --- validated staged bf16 logits tail ---
  rmsb_k<<<Tn, 256, 0, stream>>>(x, final_nw, nullptr, hb);
  f2b_k<<<2048, 256, 0, stream>>>(emb, embB, (size_t)Vn * Cn / 4);
  gemm_btl<<<dim3(Tn / 128, Vn / 128), 256, 0, stream>>>(hb, embB, nullptr, out, Tn, Vn, Cn);
}

// Round 20
// 4994.595 us; speedup vs baseline: 1.0219x; 1.0219x over previous
//
#include <hip/hip_runtime.h>
#include <hip/hip_bf16.h>
#include <math.h>

#define Tn   2048
#define Cn   1536
#define Vn   32000
#define NHn  12
#define NKVn 4
#define Dn   128
#define HIDn 2048
#define En   8
#define Kn   2
#define Ln   2
#define NREPn 3
#define EPSn 1e-6f
#define CHT  16
#define NCHn 4
#define QKVW 2560

using bf16 = __hip_bfloat16;
using bf16x8 = __attribute__((ext_vector_type(8))) short;
using f32x4v = __attribute__((ext_vector_type(4))) float;

__device__ __forceinline__ void split3(float v, short& h, short& m, short& lo) {
  bf16 b0 = __float2bfloat16(v);
  float r1 = v - __bfloat162float(b0);
  bf16 b1 = __float2bfloat16(r1);
  float r2 = r1 - __bfloat162float(b1);
  bf16 b2 = __float2bfloat16(r2);
  h = *reinterpret_cast<short*>(&b0);
  m = *reinterpret_cast<short*>(&b1);
  lo = *reinterpret_cast<short*>(&b2);
}
__device__ __forceinline__ float b2f(short s) {
  bf16 b = *reinterpret_cast<bf16*>(&s);
  return __bfloat162float(b);
}
__device__ __forceinline__ void gl_lds16(const void* g, void* l) {
  __builtin_amdgcn_global_load_lds((const __attribute__((address_space(1))) void*)g,
                                   (__attribute__((address_space(3))) void*)l, 16, 0, 0);
}

// ---------------- embed (validated) ----------------
__global__ void embed_k(const int* __restrict__ tok, const float* __restrict__ emb,
                        const float* __restrict__ pos, float* __restrict__ x) {
  int n = blockIdx.x;
  int t = threadIdx.x;
  int id = tok[n];
  const float* er = emb + (size_t)id * Cn;
  const float* pr = pos + (size_t)n * Cn;
  float* xr = x + (size_t)n * Cn;
  for (int c = t; c < Cn; c += 256) xr[c] = er[c] + pr[c];
}

// ---------------- RMSNorm -> (opt fp32) + 3-level split (validated) ----------------
__global__ void rms3_k(const float* __restrict__ x, const float* __restrict__ w,
                       float* __restrict__ outf, short* __restrict__ dh,
                       short* __restrict__ dm, short* __restrict__ dl) {
  int n = blockIdx.x, t = threadIdx.x;
  const float* xr = x + (size_t)n * Cn;
  float v[6];
  float ss = 0.f;
#pragma unroll
  for (int i = 0; i < 6; i++) { v[i] = xr[t + i * 256]; ss += v[i] * v[i]; }
  for (int off = 32; off > 0; off >>= 1) ss += __shfl_down(ss, off, 64);
  __shared__ float red[4];
  __shared__ float rtot;
  int wave = t >> 6, lane = t & 63;
  if (lane == 0) red[wave] = ss;
  __syncthreads();
  if (t == 0) rtot = rsqrtf((red[0] + red[1] + red[2] + red[3]) / (float)Cn + EPSn);
  __syncthreads();
  float r = rtot;
#pragma unroll
  for (int i = 0; i < 6; i++) {
    int c = t + i * 256;
    float val = v[i] * r * w[c];
    size_t idx = (size_t)n * Cn + c;
    if (outf) outf[idx] = val;
    short h, m, lo;
    split3(val, h, m, lo);
    dh[idx] = h; dm[idx] = m; dl[idx] = lo;
  }
}

// ---------------- RMSNorm -> (opt fp32) + bf16 (validated) ----------------
__global__ void rmsb_k(const float* __restrict__ x, const float* __restrict__ w,
                       float* __restrict__ outf, bf16* __restrict__ outb) {
  int n = blockIdx.x, t = threadIdx.x;
  const float* xr = x + (size_t)n * Cn;
  float v[6];
  float ss = 0.f;
#pragma unroll
  for (int i = 0; i < 6; i++) { v[i] = xr[t + i * 256]; ss += v[i] * v[i]; }
  for (int off = 32; off > 0; off >>= 1) ss += __shfl_down(ss, off, 64);
  __shared__ float red[4];
  __shared__ float rtot;
  int wave = t >> 6, lane = t & 63;
  if (lane == 0) red[wave] = ss;
  __syncthreads();
  if (t == 0) rtot = rsqrtf((red[0] + red[1] + red[2] + red[3]) / (float)Cn + EPSn);
  __syncthreads();
  float r = rtot;
#pragma unroll
  for (int i = 0; i < 6; i++) {
    int c = t + i * 256;
    float val = v[i] * r * w[c];
    size_t idx = (size_t)n * Cn + c;
    if (outf) outf[idx] = val;
    outb[idx] = __float2bfloat16(val);
  }
}

// ---------------- fp32 -> bf16 (validated) ----------------
__global__ void f2b_k(const float* __restrict__ s, bf16* __restrict__ d, size_t n4) {
  size_t i = (size_t)blockIdx.x * 256 + threadIdx.x;
  size_t stride = (size_t)gridDim.x * 256;
  for (; i < n4; i += stride) {
    float4 v = ((const float4*)s)[i];
    d[i * 4 + 0] = __float2bfloat16(v.x);
    d[i * 4 + 1] = __float2bfloat16(v.y);
    d[i * 4 + 2] = __float2bfloat16(v.z);
    d[i * 4 + 3] = __float2bfloat16(v.w);
  }
}

// ---------------- transpose + 3-way split (validated) ----------------
__global__ void transp3_k(const float* __restrict__ src, short* __restrict__ dh,
                          short* __restrict__ dm, short* __restrict__ dl, int K, int N) {
  __shared__ __align__(16) float ls[32][33];
  size_t boff = (size_t)blockIdx.z * K * N;
  int k0 = blockIdx.x * 32, n0 = blockIdx.y * 32;
  int t = threadIdx.x;
  int kr = t >> 3, n4 = (t & 7) * 4;
  float4 vv = *(const float4*)&src[boff + (size_t)(k0 + kr) * N + n0 + n4];
  ls[kr][n4 + 0] = vv.x; ls[kr][n4 + 1] = vv.y; ls[kr][n4 + 2] = vv.z; ls[kr][n4 + 3] = vv.w;
  __syncthreads();
  int nr = t >> 3, k4 = (t & 7) * 4;
  size_t dbase = boff + (size_t)(n0 + nr) * K + k0 + k4;
#pragma unroll
  for (int u = 0; u < 4; u++) {
    short h, m, lo;
    split3(ls[k4 + u][nr], h, m, lo);
    dh[dbase + u] = h; dm[dbase + u] = m; dl[dbase + u] = lo;
  }
}

// ---------------- single-level transpose+convert (validated) ----------------
__global__ void transp_k(const float* __restrict__ src, bf16* __restrict__ dst, int K, int N) {
  __shared__ __align__(16) float ls[32][33];
  size_t boff = (size_t)blockIdx.z * K * N;
  int k0 = blockIdx.x * 32, n0 = blockIdx.y * 32;
  int t = threadIdx.x;
  int kr = t >> 3, n4 = (t & 7) * 4;
  float4 vv = *(const float4*)&src[boff + (size_t)(k0 + kr) * N + n0 + n4];
  ls[kr][n4 + 0] = vv.x; ls[kr][n4 + 1] = vv.y; ls[kr][n4 + 2] = vv.z; ls[kr][n4 + 3] = vv.w;
  __syncthreads();
  int nr = t >> 3, k4 = (t & 7) * 4;
  bf16* drow = dst + boff + (size_t)(n0 + nr) * K + k0 + k4;
#pragma unroll
  for (int u = 0; u < 4; u++) drow[u] = __float2bfloat16(ls[k4 + u][nr]);
}

// ---------------- LDS-staged pure-bf16 MFMA GEMM (validated; logits tail) ----------------
__global__ void __launch_bounds__(256) gemm_btl(const bf16* __restrict__ A, const bf16* __restrict__ Bt,
                                                const float* res, float* Co, int M, int N, int K) {
  __shared__ __align__(16) bf16 As[128 * 32];
  __shared__ __align__(16) bf16 Bs[128 * 32];
  int t = threadIdx.x;
  int l = t & 63, w = t >> 6;
  int bm = blockIdx.x * 128, bn = blockIdx.y * 128;
  int wr = (w >> 1) * 64, wc = (w & 1) * 64;
  const f32x4v zero = {0.f, 0.f, 0.f, 0.f};
  f32x4v acc[4][4];
#pragma unroll
  for (int i = 0; i < 4; i++)
#pragma unroll
    for (int j = 0; j < 4; j++) acc[i][j] = zero;
  const bf16* ag0 = A + (size_t)(bm + (t >> 2)) * K + (t & 3) * 8;
  const bf16* ag1 = A + (size_t)(bm + 64 + (t >> 2)) * K + (t & 3) * 8;
  const bf16* bg0 = Bt + (size_t)(bn + (t >> 2)) * K + (t & 3) * 8;
  const bf16* bg1 = Bt + (size_t)(bn + 64 + (t >> 2)) * K + (t & 3) * 8;
  int rl = l & 15, ko = (l >> 4) * 8;
  for (int k0 = 0; k0 < K; k0 += 32) {
    gl_lds16(ag0 + k0, (char*)As + t * 16);
    gl_lds16(ag1 + k0, (char*)As + (256 + t) * 16);
    gl_lds16(bg0 + k0, (char*)Bs + t * 16);
    gl_lds16(bg1 + k0, (char*)Bs + (256 + t) * 16);
    __syncthreads();
    bf16x8 a[4], b[4];
#pragma unroll
    for (int i = 0; i < 4; i++) a[i] = *(const bf16x8*)(As + (wr + i * 16 + rl) * 32 + ko);
#pragma unroll
    for (int j = 0; j < 4; j++) b[j] = *(const bf16x8*)(Bs + (wc + j * 16 + rl) * 32 + ko);
#pragma unroll
    for (int i = 0; i < 4; i++)
#pragma unroll
      for (int j = 0; j < 4; j++)
        acc[i][j] = __builtin_amdgcn_mfma_f32_16x16x32_bf16(a[i], b[j], acc[i][j], 0, 0, 0);
    __syncthreads();
  }
#pragma unroll
  for (int i = 0; i < 4; i++) {
    int rbase = bm + wr + i * 16 + (l >> 4) * 4;
#pragma unroll
    for (int j = 0; j < 4; j++) {
      int col = bn + wc + j * 16 + (l & 15);
#pragma unroll
      for (int r = 0; r < 4; r++) {
        size_t idx = (size_t)(rbase + r) * N + col;
        float v = acc[i][j][r];
        if (res) v += res[idx];
        Co[idx] = v;
      }
    }
  }
}

// ---------------- LDS-staged split-fp32 GEMM (validated) ----------------
__global__ void __launch_bounds__(256) gemm6(const bf16* __restrict__ AH, const bf16* __restrict__ AM,
                                             const bf16* __restrict__ AL,
                                             const bf16* __restrict__ BH, const bf16* __restrict__ BM,
                                             const bf16* __restrict__ BL,
                                             const float* res, float* __restrict__ Co,
                                             int M, int N, int K) {
  __shared__ __align__(16) bf16 sAH[128 * 32], sAM[128 * 32], sAL[128 * 32];
  __shared__ __align__(16) bf16 sBH[128 * 32], sBM[128 * 32], sBL[128 * 32];
  int t = threadIdx.x;
  int l = t & 63, w = t >> 6;
  int bm = blockIdx.x * 128, bn = blockIdx.y * 128;
  int wr = (w >> 1) * 64, wc = (w & 1) * 64;
  const f32x4v zero = {0.f, 0.f, 0.f, 0.f};
  f32x4v acc[4][4];
#pragma unroll
  for (int i = 0; i < 4; i++)
#pragma unroll
    for (int j = 0; j < 4; j++) acc[i][j] = zero;
  size_t a0 = (size_t)(bm + (t >> 2)) * K + (t & 3) * 8;
  size_t a1 = (size_t)(bm + 64 + (t >> 2)) * K + (t & 3) * 8;
  size_t b0 = (size_t)(bn + (t >> 2)) * K + (t & 3) * 8;
  size_t b1 = (size_t)(bn + 64 + (t >> 2)) * K + (t & 3) * 8;
  int rl = l & 15, ko = (l >> 4) * 8;
  for (int k0 = 0; k0 < K; k0 += 32) {
    gl_lds16(AH + a0 + k0, (char*)sAH + t * 16);
    gl_lds16(AH + a1 + k0, (char*)sAH + (256 + t) * 16);
    gl_lds16(AM + a0 + k0, (char*)sAM + t * 16);
    gl_lds16(AM + a1 + k0, (char*)sAM + (256 + t) * 16);
    gl_lds16(AL + a0 + k0, (char*)sAL + t * 16);
    gl_lds16(AL + a1 + k0, (char*)sAL + (256 + t) * 16);
    gl_lds16(BH + b0 + k0, (char*)sBH + t * 16);
    gl_lds16(BH + b1 + k0, (char*)sBH + (256 + t) * 16);
    gl_lds16(BM + b0 + k0, (char*)sBM + t * 16);
    gl_lds16(BM + b1 + k0, (char*)sBM + (256 + t) * 16);
    gl_lds16(BL + b0 + k0, (char*)sBL + t * 16);
    gl_lds16(BL + b1 + k0, (char*)sBL + (256 + t) * 16);
    __syncthreads();
    bf16x8 aH[4], aM[4], aL[4];
#pragma unroll
    for (int i = 0; i < 4; i++) {
      int ro = (wr + i * 16 + rl) * 32 + ko;
      aH[i] = *(const bf16x8*)(sAH + ro);
      aM[i] = *(const bf16x8*)(sAM + ro);
      aL[i] = *(const bf16x8*)(sAL + ro);
    }
#pragma unroll
    for (int j = 0; j < 4; j++) {
      int ro = (wc + j * 16 + rl) * 32 + ko;
      bf16x8 bh = *(const bf16x8*)(sBH + ro);
      bf16x8 bm_ = *(const bf16x8*)(sBM + ro);
      bf16x8 bl = *(const bf16x8*)(sBL + ro);
#pragma unroll
      for (int i = 0; i < 4; i++) {
        acc[i][j] = __builtin_amdgcn_mfma_f32_16x16x32_bf16(aL[i], bh, acc[i][j], 0, 0, 0);
        acc[i][j] = __builtin_amdgcn_mfma_f32_16x16x32_bf16(aH[i], bl, acc[i][j], 0, 0, 0);
        acc[i][j] = __builtin_amdgcn_mfma_f32_16x16x32_bf16(aM[i], bm_, acc[i][j], 0, 0, 0);
        acc[i][j] = __builtin_amdgcn_mfma_f32_16x16x32_bf16(aM[i], bh, acc[i][j], 0, 0, 0);
        acc[i][j] = __builtin_amdgcn_mfma_f32_16x16x32_bf16(aH[i], bm_, acc[i][j], 0, 0, 0);
        acc[i][j] = __builtin_amdgcn_mfma_f32_16x16x32_bf16(aH[i], bh, acc[i][j], 0, 0, 0);
      }
    }
    __syncthreads();
  }
#pragma unroll
  for (int i = 0; i < 4; i++) {
    int rbase = bm + wr + i * 16 + (l >> 4) * 4;
#pragma unroll
    for (int j = 0; j < 4; j++) {
      int col = bn + wc + j * 16 + (l & 15);
#pragma unroll
      for (int r = 0; r < 4; r++) {
        size_t idx = (size_t)(rbase + r) * N + col;
        float v = acc[i][j][r];
        if (res) v += res[idx];
        Co[idx] = v;
      }
    }
  }
}

// ---------------- LDS-staged split-fp32 MoE expert GEMM (validated; layer 0) ----------------
__global__ void __launch_bounds__(256) mexp6(const bf16* __restrict__ AH, const bf16* __restrict__ AM,
                                             const bf16* __restrict__ AL,
                                             const bf16* __restrict__ BH, const bf16* __restrict__ BM,
                                             const bf16* __restrict__ BL,
                                             const int* __restrict__ perm, const int* __restrict__ cnt,
                                             int ebase,
                                             short* __restrict__ HH, short* __restrict__ HM,
                                             short* __restrict__ HL,
                                             float* __restrict__ Co, int K, int N, int mode) {
  int e = ebase + blockIdx.z;
  int nrows = cnt[e];
  int bm = blockIdx.x * 128;
  if (bm >= nrows) return;
  int bn = blockIdx.y * 128;
  size_t eoff = (size_t)blockIdx.z * K * N;
  __shared__ __align__(16) bf16 sAH[128 * 32], sAM[128 * 32], sAL[128 * 32];
  __shared__ __align__(16) bf16 sBH[128 * 32], sBM[128 * 32], sBL[128 * 32];
  __shared__ int prow[128];
  int t = threadIdx.x, l = t & 63, w = t >> 6;
  if (t < 128) {
    int i = bm + t;
    prow[t] = (i < nrows) ? perm[e * Tn + i] : -1;
  }
  __syncthreads();
  int wr = (w >> 1) * 64, wc = (w & 1) * 64;
  const f32x4v zero = {0.f, 0.f, 0.f, 0.f};
  f32x4v acc[4][4];
#pragma unroll
  for (int i = 0; i < 4; i++)
#pragma unroll
    for (int j = 0; j < 4; j++) acc[i][j] = zero;
  int p0 = prow[t >> 2], p1 = prow[64 + (t >> 2)];
  int g0r = (p0 >= 0) ? (mode == 2 ? p0 : (p0 >> 1)) : 0;
  int g1r = (p1 >= 0) ? (mode == 2 ? p1 : (p1 >> 1)) : 0;
  size_t a0 = (size_t)g0r * K + (t & 3) * 8;
  size_t a1 = (size_t)g1r * K + (t & 3) * 8;
  size_t b0 = eoff + (size_t)(bn + (t >> 2)) * K + (t & 3) * 8;
  size_t b1 = eoff + (size_t)(bn + 64 + (t >> 2)) * K + (t & 3) * 8;
  int rl = l & 15, ko = (l >> 4) * 8;
  for (int k0 = 0; k0 < K; k0 += 32) {
    gl_lds16(AH + a0 + k0, (char*)sAH + t * 16);
    gl_lds16(AH + a1 + k0, (char*)sAH + (256 + t) * 16);
    gl_lds16(AM + a0 + k0, (char*)sAM + t * 16);
    gl_lds16(AM + a1 + k0, (char*)sAM + (256 + t) * 16);
    gl_lds16(AL + a0 + k0, (char*)sAL + t * 16);
    gl_lds16(AL + a1 + k0, (char*)sAL + (256 + t) * 16);
    gl_lds16(BH + b0 + k0, (char*)sBH + t * 16);
    gl_lds16(BH + b1 + k0, (char*)sBH + (256 + t) * 16);
    gl_lds16(BM + b0 + k0, (char*)sBM + t * 16);
    gl_lds16(BM + b1 + k0, (char*)sBM + (256 + t) * 16);
    gl_lds16(BL + b0 + k0, (char*)sBL + t * 16);
    gl_lds16(BL + b1 + k0, (char*)sBL + (256 + t) * 16);
    __syncthreads();
    bf16x8 aH[4], aM[4], aL[4];
#pragma unroll
    for (int i = 0; i < 4; i++) {
      int ro = (wr + i * 16 + rl) * 32 + ko;
      aH[i] = *(const bf16x8*)(sAH + ro);
      aM[i] = *(const bf16x8*)(sAM + ro);
      aL[i] = *(const bf16x8*)(sAL + ro);
    }
#pragma unroll
    for (int j = 0; j < 4; j++) {
      int ro = (wc + j * 16 + rl) * 32 + ko;
      bf16x8 bh = *(const bf16x8*)(sBH + ro);
      bf16x8 bm_ = *(const bf16x8*)(sBM + ro);
      bf16x8 bl = *(const bf16x8*)(sBL + ro);
#pragma unroll
      for (int i = 0; i < 4; i++) {
        acc[i][j] = __builtin_amdgcn_mfma_f32_16x16x32_bf16(aL[i], bh, acc[i][j], 0, 0, 0);
        acc[i][j] = __builtin_amdgcn_mfma_f32_16x16x32_bf16(aH[i], bl, acc[i][j], 0, 0, 0);
        acc[i][j] = __builtin_amdgcn_mfma_f32_16x16x32_bf16(aM[i], bm_, acc[i][j], 0, 0, 0);
        acc[i][j] = __builtin_amdgcn_mfma_f32_16x16x32_bf16(aM[i], bh, acc[i][j], 0, 0, 0);
        acc[i][j] = __builtin_amdgcn_mfma_f32_16x16x32_bf16(aH[i], bm_, acc[i][j], 0, 0, 0);
        acc[i][j] = __builtin_amdgcn_mfma_f32_16x16x32_bf16(aH[i], bh, acc[i][j], 0, 0, 0);
      }
    }
    __syncthreads();
  }
#pragma unroll
  for (int i = 0; i < 4; i++) {
#pragma unroll
    for (int r = 0; r < 4; r++) {
      int lrow = wr + i * 16 + (l >> 4) * 4 + r;
      int p = prow[lrow];
      if (p < 0) continue;
#pragma unroll
      for (int j = 0; j < 4; j++) {
        int col = bn + wc + j * 16 + (l & 15);
        size_t idx = (size_t)p * N + col;
        float v = acc[i][j][r];
        if (mode == 0) {
          short h, m, lo;
          split3(v, h, m, lo);
          HH[idx] = h; HM[idx] = m; HL[idx] = lo;
        } else if (mode == 1) {
          float v1 = b2f(HH[idx]) + b2f(HM[idx]) + b2f(HL[idx]);
          float hh = (v1 / (1.f + expf(-v1))) * v;
          short h, m, lo;
          split3(hh, h, m, lo);
          HH[idx] = h; HM[idx] = m; HL[idx] = lo;
        } else {
          Co[idx] = v;
        }
      }
    }
  }
}

// ---------------- DUAL-B bf16 MoE up-proj (validated; layer 1) ----------------
__global__ void __launch_bounds__(256) mexpBd(const bf16* __restrict__ A, const bf16* __restrict__ B1,
                                              const bf16* __restrict__ B3,
                                              const int* __restrict__ perm, const int* __restrict__ cnt,
                                              int ebase, bf16* __restrict__ HB, int K, int N) {
  int e = ebase + blockIdx.z;
  int nrows = cnt[e];
  int bm = blockIdx.x * 128;
  if (bm >= nrows) return;
  int bn = blockIdx.y * 128;
  size_t eoff = (size_t)blockIdx.z * K * N;
  __shared__ __align__(16) bf16 sA[128 * 32];
  __shared__ __align__(16) bf16 s1[128 * 32];
  __shared__ __align__(16) bf16 s3[128 * 32];
  __shared__ int prow[128];
  int t = threadIdx.x, l = t & 63, w = t >> 6;
  if (t < 128) {
    int i = bm + t;
    prow[t] = (i < nrows) ? perm[e * Tn + i] : -1;
  }
  __syncthreads();
  int wr = (w >> 1) * 64, wc = (w & 1) * 64;
  const f32x4v zero = {0.f, 0.f, 0.f, 0.f};
  f32x4v acc1[4][4], acc3[4][4];
#pragma unroll
  for (int i = 0; i < 4; i++)
#pragma unroll
    for (int j = 0; j < 4; j++) { acc1[i][j] = zero; acc3[i][j] = zero; }
  int p0 = prow[t >> 2], p1 = prow[64 + (t >> 2)];
  int g0r = (p0 >= 0) ? (p0 >> 1) : 0;
  int g1r = (p1 >= 0) ? (p1 >> 1) : 0;
  size_t a0 = (size_t)g0r * K + (t & 3) * 8;
  size_t a1 = (size_t)g1r * K + (t & 3) * 8;
  size_t b0 = eoff + (size_t)(bn + (t >> 2)) * K + (t & 3) * 8;
  size_t b1 = eoff + (size_t)(bn + 64 + (t >> 2)) * K + (t & 3) * 8;
  int rl = l & 15, ko = (l >> 4) * 8;
  for (int k0 = 0; k0 < K; k0 += 32) {
    gl_lds16(A + a0 + k0, (char*)sA + t * 16);
    gl_lds16(A + a1 + k0, (char*)sA + (256 + t) * 16);
    gl_lds16(B1 + b0 + k0, (char*)s1 + t * 16);
    gl_lds16(B1 + b1 + k0, (char*)s1 + (256 + t) * 16);
    gl_lds16(B3 + b0 + k0, (char*)s3 + t * 16);
    gl_lds16(B3 + b1 + k0, (char*)s3 + (256 + t) * 16);
    __syncthreads();
    bf16x8 a[4];
#pragma unroll
    for (int i = 0; i < 4; i++) a[i] = *(const bf16x8*)(sA + (wr + i * 16 + rl) * 32 + ko);
#pragma unroll
    for (int j = 0; j < 4; j++) {
      int ro = (wc + j * 16 + rl) * 32 + ko;
      bf16x8 b1v = *(const bf16x8*)(s1 + ro);
      bf16x8 b3v = *(const bf16x8*)(s3 + ro);
#pragma unroll
      for (int i = 0; i < 4; i++) {
        acc1[i][j] = __builtin_amdgcn_mfma_f32_16x16x32_bf16(a[i], b1v, acc1[i][j], 0, 0, 0);
        acc3[i][j] = __builtin_amdgcn_mfma_f32_16x16x32_bf16(a[i], b3v, acc3[i][j], 0, 0, 0);
      }
    }
    __syncthreads();
  }
#pragma unroll
  for (int i = 0; i < 4; i++) {
#pragma unroll
    for (int r = 0; r < 4; r++) {
      int lrow = wr + i * 16 + (l >> 4) * 4 + r;
      int p = prow[lrow];
      if (p < 0) continue;
#pragma unroll
      for (int j = 0; j < 4; j++) {
        int col = bn + wc + j * 16 + (l & 15);
        float h1 = acc1[i][j][r], h3 = acc3[i][j][r];
        HB[(size_t)p * N + col] = __float2bfloat16((h1 / (1.f + expf(-h1))) * h3);
      }
    }
  }
}

// ---------------- bf16 MoE expert GEMM (validated; layer-1 down-proj) ----------------
__global__ void __launch_bounds__(256) mexpB(const bf16* __restrict__ A, const bf16* __restrict__ B,
                                             const int* __restrict__ perm, const int* __restrict__ cnt,
                                             int ebase, float* __restrict__ Co, int K, int N) {
  int e = ebase + blockIdx.z;
  int nrows = cnt[e];
  int bm = blockIdx.x * 128;
  if (bm >= nrows) return;
  int bn = blockIdx.y * 128;
  size_t eoff = (size_t)blockIdx.z * K * N;
  __shared__ __align__(16) bf16 sA[128 * 32];
  __shared__ __align__(16) bf16 sB[128 * 32];
  __shared__ int prow[128];
  int t = threadIdx.x, l = t & 63, w = t >> 6;
  if (t < 128) {
    int i = bm + t;
    prow[t] = (i < nrows) ? perm[e * Tn + i] : -1;
  }
  __syncthreads();
  int wr = (w >> 1) * 64, wc = (w & 1) * 64;
  const f32x4v zero = {0.f, 0.f, 0.f, 0.f};
  f32x4v acc[4][4];
#pragma unroll
  for (int i = 0; i < 4; i++)
#pragma unroll
    for (int j = 0; j < 4; j++) acc[i][j] = zero;
  int p0 = prow[t >> 2], p1 = prow[64 + (t >> 2)];
  int g0r = (p0 >= 0) ? p0 : 0;
  int g1r = (p1 >= 0) ? p1 : 0;
  size_t a0 = (size_t)g0r * K + (t & 3) * 8;
  size_t a1 = (size_t)g1r * K + (t & 3) * 8;
  size_t b0 = eoff + (size_t)(bn + (t >> 2)) * K + (t & 3) * 8;
  size_t b1 = eoff + (size_t)(bn + 64 + (t >> 2)) * K + (t & 3) * 8;
  int rl = l & 15, ko = (l >> 4) * 8;
  for (int k0 = 0; k0 < K; k0 += 32) {
    gl_lds16(A + a0 + k0, (char*)sA + t * 16);
    gl_lds16(A + a1 + k0, (char*)sA + (256 + t) * 16);
    gl_lds16(B + b0 + k0, (char*)sB + t * 16);
    gl_lds16(B + b1 + k0, (char*)sB + (256 + t) * 16);
    __syncthreads();
    bf16x8 a[4], b[4];
#pragma unroll
    for (int i = 0; i < 4; i++) a[i] = *(const bf16x8*)(sA + (wr + i * 16 + rl) * 32 + ko);
#pragma unroll
    for (int j = 0; j < 4; j++) b[j] = *(const bf16x8*)(sB + (wc + j * 16 + rl) * 32 + ko);
#pragma unroll
    for (int i = 0; i < 4; i++)
#pragma unroll
      for (int j = 0; j < 4; j++)
        acc[i][j] = __builtin_amdgcn_mfma_f32_16x16x32_bf16(a[i], b[j], acc[i][j], 0, 0, 0);
    __syncthreads();
  }
#pragma unroll
  for (int i = 0; i < 4; i++) {
#pragma unroll
    for (int r = 0; r < 4; r++) {
      int lrow = wr + i * 16 + (l >> 4) * 4 + r;
      int p = prow[lrow];
      if (p < 0) continue;
#pragma unroll
      for (int j = 0; j < 4; j++) {
        int col = bn + wc + j * 16 + (l & 15);
        Co[(size_t)p * N + col] = acc[i][j][r];
      }
    }
  }
}

// ---------------- split-K flash attention: fixed-chunk partial pass (best measured) ----------------
__global__ void __launch_bounds__(256) attn_part_k(const float* __restrict__ qkv,
                                                   float* __restrict__ po,
                                                   float* __restrict__ pm,
                                                   float* __restrict__ pl) {
  int qt = blockIdx.x;
  int head = blockIdx.y;
  int ch = blockIdx.z;
  int ntiles = qt + 1;
  int tA = ch * CHT;
  int t = threadIdx.x;
  int r = t >> 3, g = t & 7, d0 = g * 16;
  int q0 = qt * 32;
  int row = q0 + r;
  size_t pidx = ((size_t)head * Tn + row) * NCHn + ch;
  if (tA >= ntiles) {
    if (g == 0) { pm[pidx] = -1e30f; pl[pidx] = 0.f; }
    float* porow = po + pidx * Dn + d0;
#pragma unroll
    for (int j = 0; j < 16; j += 4) {
      float4 z = {0.f, 0.f, 0.f, 0.f};
      *(float4*)(porow + j) = z;
    }
    return;
  }
  int tB = tA + CHT < ntiles ? tA + CHT : ntiles;
  int kvh = head / NREPn;
  __shared__ __align__(16) float ks[32][Dn + 4];
  __shared__ __align__(16) float vs[32][Dn + 4];
  const float scale = 0.08838834764831845f;
  float qr[16];
  {
    const float* qrow = qkv + (size_t)row * QKVW + head * Dn + d0;
#pragma unroll
    for (int j = 0; j < 16; j += 4) {
      float4 u = *(const float4*)(qrow + j);
      qr[j] = u.x * scale; qr[j + 1] = u.y * scale;
      qr[j + 2] = u.z * scale; qr[j + 3] = u.w * scale;
    }
  }
  float o[16];
#pragma unroll
  for (int j = 0; j < 16; j++) o[j] = 0.f;
  float rowm = -1e30f, rowl = 0.f;

  for (int kt = tA; kt < tB; kt++) {
    int kv0 = kt * 32;
    for (int e = t; e < 32 * 32; e += 256) {
      int rr = e >> 5, c4 = (e & 31) * 4;
      size_t base = (size_t)(kv0 + rr) * QKVW + kvh * Dn + c4;
      *(float4*)&ks[rr][c4] = *(const float4*)(qkv + base + 1536);
      *(float4*)&vs[rr][c4] = *(const float4*)(qkv + base + 2048);
    }
    __syncthreads();
    float s[32];
#pragma unroll
    for (int kk = 0; kk < 32; kk++) {
      const float* krow = &ks[kk][d0];
      float p = 0.f;
#pragma unroll
      for (int j = 0; j < 16; j += 4) {
        float4 u = *(const float4*)(krow + j);
        p += qr[j] * u.x + qr[j + 1] * u.y + qr[j + 2] * u.z + qr[j + 3] * u.w;
      }
      p += __shfl_xor(p, 1);
      p += __shfl_xor(p, 2);
      p += __shfl_xor(p, 4);
      s[kk] = p;
    }
    if (kt == qt) {
#pragma unroll
      for (int kk = 0; kk < 32; kk++)
        if (kv0 + kk > row) s[kk] = -1e30f;
    }
    float mx = s[0];
#pragma unroll
    for (int kk = 1; kk < 32; kk++) mx = fmaxf(mx, s[kk]);
    float m_new = fmaxf(rowm, mx);
    float corr = expf(rowm - m_new);
    float sum = 0.f;
#pragma unroll
    for (int kk = 0; kk < 32; kk++) { s[kk] = expf(s[kk] - m_new); sum += s[kk]; }
    rowl = rowl * corr + sum;
    rowm = m_new;
#pragma unroll
    for (int j = 0; j < 16; j++) o[j] *= corr;
#pragma unroll
    for (int kk = 0; kk < 32; kk++) {
      float p = s[kk];
      const float* vrow = &vs[kk][d0];
#pragma unroll
      for (int j = 0; j < 16; j += 4) {
        float4 u = *(const float4*)(vrow + j);
        o[j] += p * u.x; o[j + 1] += p * u.y; o[j + 2] += p * u.z; o[j + 3] += p * u.w;
      }
    }
    __syncthreads();
  }
  if (g == 0) { pm[pidx] = rowm; pl[pidx] = rowl; }
  float* porow = po + pidx * Dn + d0;
#pragma unroll
  for (int j = 0; j < 16; j += 4) {
    float4 u;
    u.x = o[j]; u.y = o[j + 1]; u.z = o[j + 2]; u.w = o[j + 3];
    *(float4*)(porow + j) = u;
  }
}

// ---------------- split-K merge -> split-3 levels (validated) ----------------
__global__ void __launch_bounds__(256) attn_merge3_k(const float* __restrict__ po,
                                                     const float* __restrict__ pm,
                                                     const float* __restrict__ pl,
                                                     short* __restrict__ dh,
                                                     short* __restrict__ dm,
                                                     short* __restrict__ dl) {
  int qt = blockIdx.x;
  int head = blockIdx.y;
  int q0 = qt * 32;
  int t = threadIdx.x;
  int r = t >> 3, g = t & 7, d0 = g * 16;
  int row = q0 + r;
  size_t base = ((size_t)head * Tn + row) * NCHn;
  float M = -1e30f;
#pragma unroll
  for (int c = 0; c < NCHn; c++) M = fmaxf(M, pm[base + c]);
  float L = 0.f;
  float acc[16];
#pragma unroll
  for (int j = 0; j < 16; j++) acc[j] = 0.f;
#pragma unroll
  for (int c = 0; c < NCHn; c++) {
    float wgt = expf(pm[base + c] - M);
    L += pl[base + c] * wgt;
    const float* p = po + (base + c) * Dn + d0;
#pragma unroll
    for (int j = 0; j < 16; j += 4) {
      float4 u = *(const float4*)(p + j);
      acc[j] += wgt * u.x; acc[j + 1] += wgt * u.y;
      acc[j + 2] += wgt * u.z; acc[j + 3] += wgt * u.w;
    }
  }
  float inv = 1.f / L;
  size_t yidx = (size_t)row * Cn + head * Dn + d0;
#pragma unroll
  for (int j = 0; j < 16; j++) {
    short h, m, lo;
    split3(acc[j] * inv, h, m, lo);
    dh[yidx + j] = h; dm[yidx + j] = m; dl[yidx + j] = lo;
  }
}

// ---------------- gate logits (validated) ----------------
__global__ void gate_k(const float* __restrict__ xf, const float* __restrict__ g,
                       float* __restrict__ gl) {
  int n = blockIdx.x, t = threadIdx.x;
  int e = t & 7, cs = t >> 3;
  const float* xr = xf + (size_t)n * Cn;
  float s = 0.f;
  for (int j = 0; j < Cn / 32; j++) {
    int c = cs + 32 * j;
    s += xr[c] * g[c * En + e];
  }
  __shared__ float red[256];
  red[t] = s;
  __syncthreads();
  if (t < 8) {
    float tot = 0.f;
    for (int j = 0; j < 32; j++) tot += red[t + 8 * j];
    gl[n * En + t] = tot;
  }
}

// ---------------- routing (validated, Tn stride) ----------------
__global__ void route_k(const float* __restrict__ gl, float* __restrict__ topw,
                        int* __restrict__ cnt, int* __restrict__ perm) {
  int n = blockIdx.x * blockDim.x + threadIdx.x;
  if (n >= Tn) return;
  float p[En];
  float mx = -1e30f;
#pragma unroll
  for (int e = 0; e < En; e++) { p[e] = gl[n * En + e]; mx = fmaxf(mx, p[e]); }
  float s = 0.f;
#pragma unroll
  for (int e = 0; e < En; e++) { p[e] = expf(p[e] - mx); s += p[e]; }
  float invs = 1.f / s;
#pragma unroll
  for (int e = 0; e < En; e++) p[e] *= invs;
  int i0 = 0;
#pragma unroll
  for (int e = 1; e < En; e++) if (p[e] > p[i0]) i0 = e;
  int i1 = (i0 == 0) ? 1 : 0;
#pragma unroll
  for (int e = 0; e < En; e++) if (e != i0 && p[e] > p[i1]) i1 = e;
  float w0 = p[i0], w1 = p[i1], sw = w0 + w1;
  topw[2 * n]     = w0 / sw;
  topw[2 * n + 1] = w1 / sw;
  int pos0 = atomicAdd(&cnt[i0], 1);
  perm[i0 * Tn + pos0] = 2 * n;
  int pos1 = atomicAdd(&cnt[i1], 1);
  perm[i1 * Tn + pos1] = 2 * n + 1;
}

// ---------------- combine (validated) ----------------
__global__ void combine_k(const float* __restrict__ pairout, const float* __restrict__ topw,
                          float* __restrict__ x) {
  int n = blockIdx.x, t = threadIdx.x;
  float w0 = topw[2 * n], w1 = topw[2 * n + 1];
  const float* p0 = pairout + (size_t)(2 * n) * Cn;
  const float* p1 = pairout + (size_t)(2 * n + 1) * Cn;
  float* xr = x + (size_t)n * Cn;
  for (int c = t; c < Cn; c += 256) xr[c] += w0 * p0[c] + w1 * p1[c];
}

// =================================================================================
extern "C" void kernel_launch(void* const* d_in, const int* in_sizes, int n_in,
                              void* d_out, int out_size, void* d_ws, size_t ws_size,
                              hipStream_t stream) {
  const int*   tokens = (const int*)d_in[0];
  const float* emb    = (const float*)d_in[1];
  const float* pos    = (const float*)d_in[2];
  const float* wq     = (const float*)d_in[3];
  const float* wk     = (const float*)d_in[4];
  const float* wv     = (const float*)d_in[5];
  const float* wo     = (const float*)d_in[6];
  const float* attn_nw= (const float*)d_in[7];
  const float* ffn_nw = (const float*)d_in[8];
  const float* gate   = (const float*)d_in[9];
  const float* ew1    = (const float*)d_in[10];
  const float* ew2    = (const float*)d_in[11];
  const float* ew3    = (const float*)d_in[12];
  const float* final_nw = (const float*)d_in[13];
  float* out = (float*)d_out;

  char* wsb = (char*)d_ws;
  const size_t NC = (size_t)Tn * Cn;
  size_t off = 0;
  auto alloc = [&](size_t bytes) -> size_t {
    off = (off + 255) & ~(size_t)255;
    size_t p = off;
    off += bytes;
    return p;
  };
  size_t o_x    = alloc(NC * 4);
  size_t o_h    = alloc(NC * 4);
  size_t o_gl   = alloc((size_t)Tn * En * 4);
  size_t o_topw = alloc((size_t)Tn * Kn * 4);
  size_t o_cnt  = alloc(64);
  size_t o_perm = alloc((size_t)En * Tn * 4);
  size_t wlvl   = (size_t)4 * Cn * HIDn * 2;
  size_t o_w    = alloc(3 * wlvl);
  size_t hs_lvl = NC * 2;
  size_t o_hs   = alloc(3 * hs_lvl);
  size_t o_qkv  = alloc((size_t)Tn * QKVW * 4);
  size_t o_yb   = alloc(NC * 4);
  size_t hb_lvl = (size_t)Tn * Kn * HIDn * 2;
  size_t o_hbs  = o_qkv;
  size_t end_hbs = o_hbs + 3 * hb_lvl;
  if (off < end_hbs) off = end_hbs;
  size_t o_pair = alloc(NC * 4);
  size_t o_po   = alloc((size_t)NHn * Tn * NCHn * Dn * 4);   // 50.3 MB at NCHn=4
  size_t o_pm   = alloc((size_t)NHn * Tn * NCHn * 4);
  size_t o_pl   = alloc((size_t)NHn * Tn * NCHn * 4);

  float* x       = (float*)(wsb + o_x);
  float* h       = (float*)(wsb + o_h);
  float* gl      = (float*)(wsb + o_gl);
  float* topw    = (float*)(wsb + o_topw);
  int*   cnt     = (int*)(wsb + o_cnt);
  int*   perm    = (int*)(wsb + o_perm);
  float* qkvb    = (float*)(wsb + o_qkv);
  float* pairout = (float*)(wsb + o_pair);
  bf16*  hb      = (bf16*)(wsb + o_pair);
  bf16*  embB    = (bf16*)(wsb + o_w);
  float* po      = (float*)(wsb + o_po);
  float* pm      = (float*)(wsb + o_pm);
  float* pl      = (float*)(wsb + o_pl);

  short* hs[3]; short* hbs[3]; short* ewT[3];
  for (int s = 0; s < 3; s++) {
    hs[s]  = (short*)(wsb + o_hs + (size_t)s * hs_lvl);
    hbs[s] = (short*)(wsb + o_hbs + (size_t)s * hb_lvl);
    ewT[s] = (short*)(wsb + o_w + (size_t)s * wlvl);
  }
  size_t qkvw_lvl = (size_t)QKVW * Cn * 2;
  size_t wo_lvl   = (size_t)Cn * Cn * 2;
  short* qkvT[3]; short* woT[3];
  for (int s = 0; s < 3; s++) {
    qkvT[s] = (short*)(wsb + o_w + (size_t)s * qkvw_lvl);
    woT[s]  = (short*)(wsb + o_w + 3 * qkvw_lvl + (size_t)s * wo_lvl);
  }
  bf16* ew1B = (bf16*)(wsb + o_w);
  bf16* ew3B = (bf16*)(wsb + o_w + wlvl);
  bf16* ew2B = (bf16*)(wsb + o_w);

  embed_k<<<Tn, 256, 0, stream>>>(tokens, emb, pos, x);
  for (int l = 0; l < Ln; l++) {
    const float* wq_l = wq + (size_t)l * Cn * (NHn * Dn);
    const float* wk_l = wk + (size_t)l * Cn * (NKVn * Dn);
    const float* wv_l = wv + (size_t)l * Cn * (NKVn * Dn);
    const float* wo_l = wo + (size_t)l * Cn * Cn;
    const float* g_l  = gate + (size_t)l * Cn * En;
    const float* e1_l = ew1 + (size_t)l * En * Cn * HIDn;
    const float* e2_l = ew2 + (size_t)l * En * HIDn * Cn;
    const float* e3_l = ew3 + (size_t)l * En * Cn * HIDn;

    // --- attention: fused QKV split-GEMM + fixed-chunk split-K fp32 core ---
    transp3_k<<<dim3(Cn / 32, (NHn * Dn) / 32, 1), 256, 0, stream>>>(wq_l, qkvT[0], qkvT[1], qkvT[2], Cn, NHn * Dn);
    transp3_k<<<dim3(Cn / 32, (NKVn * Dn) / 32, 1), 256, 0, stream>>>(
        wk_l, qkvT[0] + (size_t)1536 * Cn, qkvT[1] + (size_t)1536 * Cn, qkvT[2] + (size_t)1536 * Cn, Cn, NKVn * Dn);
    transp3_k<<<dim3(Cn / 32, (NKVn * Dn) / 32, 1), 256, 0, stream>>>(
        wv_l, qkvT[0] + (size_t)2048 * Cn, qkvT[1] + (size_t)2048 * Cn, qkvT[2] + (size_t)2048 * Cn, Cn, NKVn * Dn);
    transp3_k<<<dim3(Cn / 32, Cn / 32, 1), 256, 0, stream>>>(wo_l, woT[0], woT[1], woT[2], Cn, Cn);
    rms3_k<<<Tn, 256, 0, stream>>>(x, attn_nw + (size_t)l * Cn, nullptr, hs[0], hs[1], hs[2]);
    gemm6<<<dim3(Tn / 128, QKVW / 128), 256, 0, stream>>>(
        (bf16*)hs[0], (bf16*)hs[1], (bf16*)hs[2], (bf16*)qkvT[0], (bf16*)qkvT[1], (bf16*)qkvT[2],
        nullptr, qkvb, Tn, QKVW, Cn);
    attn_part_k<<<dim3(Tn / 32, NHn, NCHn), 256, 0, stream>>>(qkvb, po, pm, pl);
    attn_merge3_k<<<dim3(Tn / 32, NHn), 256, 0, stream>>>(po, pm, pl, hs[0], hs[1], hs[2]);
    gemm6<<<dim3(Tn / 128, Cn / 128), 256, 0, stream>>>(
        (bf16*)hs[0], (bf16*)hs[1], (bf16*)hs[2], (bf16*)woT[0], (bf16*)woT[1], (bf16*)woT[2],
        x, x, Tn, Cn, Cn);

    if (l < Ln - 1) {
      // --- layer-0 MoE: fp32 routing + three-pass split-fp32 experts ---
      rms3_k<<<Tn, 256, 0, stream>>>(x, ffn_nw + (size_t)l * Cn, h, hs[0], hs[1], hs[2]);
      gate_k<<<Tn, 256, 0, stream>>>(h, g_l, gl);
      hipMemsetAsync(cnt, 0, 64, stream);
      route_k<<<Tn / 256, 256, 0, stream>>>(gl, topw, cnt, perm);
      for (int half = 0; half < 2; half++) {
        size_t hoff = (size_t)half * 4 * Cn * HIDn;
        int eb = half * 4;
        transp3_k<<<dim3(Cn / 32, HIDn / 32, 4), 256, 0, stream>>>(e1_l + hoff, ewT[0], ewT[1], ewT[2], Cn, HIDn);
        mexp6<<<dim3(Tn / 128, HIDn / 128, 4), 256, 0, stream>>>(
            (bf16*)hs[0], (bf16*)hs[1], (bf16*)hs[2], (bf16*)ewT[0], (bf16*)ewT[1], (bf16*)ewT[2],
            perm, cnt, eb, hbs[0], hbs[1], hbs[2], nullptr, Cn, HIDn, 0);
        transp3_k<<<dim3(Cn / 32, HIDn / 32, 4), 256, 0, stream>>>(e3_l + hoff, ewT[0], ewT[1], ewT[2], Cn, HIDn);
        mexp6<<<dim3(Tn / 128, HIDn / 128, 4), 256, 0, stream>>>(
            (bf16*)hs[0], (bf16*)hs[1], (bf16*)hs[2], (bf16*)ewT[0], (bf16*)ewT[1], (bf16*)ewT[2],
            perm, cnt, eb, hbs[0], hbs[1], hbs[2], nullptr, Cn, HIDn, 1);
        transp3_k<<<dim3(HIDn / 32, Cn / 32, 4), 256, 0, stream>>>(e2_l + (size_t)half * 4 * HIDn * Cn, ewT[0], ewT[1], ewT[2], HIDn, Cn);
        mexp6<<<dim3(Tn / 128, Cn / 128, 4), 256, 0, stream>>>(
            (bf16*)hbs[0], (bf16*)hbs[1], (bf16*)hbs[2], (bf16*)ewT[0], (bf16*)ewT[1], (bf16*)ewT[2],
            perm, cnt, eb, hbs[0], hbs[1], hbs[2], pairout, HIDn, Cn, 2);
      }
    } else {
      // --- layer-1 MoE: fp32 routing + dual-B bf16 experts ---
      bf16* hbf = (bf16*)hs[0];
      bf16* hbB = (bf16*)hbs[0];
      rmsb_k<<<Tn, 256, 0, stream>>>(x, ffn_nw + (size_t)l * Cn, h, hbf);
      gate_k<<<Tn, 256, 0, stream>>>(h, g_l, gl);
      hipMemsetAsync(cnt, 0, 64, stream);
      route_k<<<Tn / 256, 256, 0, stream>>>(gl, topw, cnt, perm);
      for (int half = 0; half < 2; half++) {
        size_t hoff = (size_t)half * 4 * Cn * HIDn;
        int eb = half * 4;
        transp_k<<<dim3(Cn / 32, HIDn / 32, 4), 256, 0, stream>>>(e1_l + hoff, ew1B, Cn, HIDn);
        transp_k<<<dim3(Cn / 32, HIDn / 32, 4), 256, 0, stream>>>(e3_l + hoff, ew3B, Cn, HIDn);
        mexpBd<<<dim3(Tn / 128, HIDn / 128, 4), 256, 0, stream>>>(
            hbf, ew1B, ew3B, perm, cnt, eb, hbB, Cn, HIDn);
        transp_k<<<dim3(HIDn / 32, Cn / 32, 4), 256, 0, stream>>>(e2_l + (size_t)half * 4 * HIDn * Cn, ew2B, HIDn, Cn);
        mexpB<<<dim3(Tn / 128, Cn / 128, 4), 256, 0, stream>>>(
            hbB, ew2B, perm, cnt, eb, pairout, HIDn, Cn);
      }
    }
    combine_k<<<Tn, 256, 0, stream>>>(pairout, topw, x);
  }
  // --- validated staged bf16 logits tail ---
  rmsb_k<<<Tn, 256, 0, stream>>>(x, final_nw, nullptr, hb);
  f2b_k<<<2048, 256, 0, stream>>>(emb, embB, (size_t)Vn * Cn / 4);
  gemm_btl<<<dim3(Tn / 128, Vn / 128), 256, 0, stream>>>(hb, embB, nullptr, out, Tn, Vn, Cn);
}